// Round 7
// baseline (542.255 us; speedup 1.0000x reference)
//
#include <hip/hip_runtime.h>
#include <math.h>

// Problem constants (fixed by reference)
#define BB   2
#define TT   4096            // tokens per batch
#define NT   (BB*TT)         // 8192 total rows
#define DD   1024
#define CQ   128             // k_query dim
#define TK   8               // top_k
#define NCH  16              // s-splits (partial top-8 lists per query)

// tie-break-aware insert (value desc, index asc) == jax.lax.top_k order
__device__ __forceinline__ void topk8_insert(float (&v)[TK], int (&ix)[TK],
                                             float val, int idx) {
    float cv = val; int ci = idx;
#pragma unroll
    for (int i = 0; i < TK; ++i) {
        bool sw = (cv > v[i]) || (cv == v[i] && ci < ix[i]);
        float tv = v[i]; int ti = ix[i];
        v[i]  = sw ? cv : tv;  ix[i] = sw ? ci : ti;
        cv    = sw ? tv : cv;  ci    = sw ? ti : ci;
    }
}

// f64 tie-break-aware insert (final exact ranking)
__device__ __forceinline__ void topk8d_insert(double (&v)[TK], int (&ix)[TK],
                                              double val, int idx) {
    double cv = val; int ci = idx;
#pragma unroll
    for (int i = 0; i < TK; ++i) {
        bool sw = (cv > v[i]) || (cv == v[i] && ci < ix[i]);
        double tv = v[i]; int ti = ix[i];
        v[i]  = sw ? cv : tv;  ix[i] = sw ? ci : ti;
        cv    = sw ? tv : cv;  ci    = sw ? ti : ci;
    }
}

// ---------------------------------------------------------------------------
// K1: q = x@Wq + bq ; k = x@Wk + bk   (f32, W broadcast via uniform loads)
// ---------------------------------------------------------------------------
__global__ __launch_bounds__(256) void proj_kernel(
    const float* __restrict__ x,
    const float* __restrict__ Wq, const float* __restrict__ bq,
    const float* __restrict__ Wk, const float* __restrict__ bk,
    float* __restrict__ q, float* __restrict__ k)
{
    int row = blockIdx.x * 256 + threadIdx.x;        // 0..NT-1
    int cc  = blockIdx.y * 16;                       // combined col 0..255
    bool isK = cc >= CQ;
    const float* W    = isK ? Wk : Wq;
    const float* bias = isK ? bk : bq;
    int c0 = isK ? cc - CQ : cc;

    float acc[16];
#pragma unroll
    for (int j = 0; j < 16; ++j) acc[j] = 0.f;

    const float* xr = x + (size_t)row * DD;
    for (int d0 = 0; d0 < DD; d0 += 4) {
        float4 xv = *reinterpret_cast<const float4*>(xr + d0);
        const float* w0 = W + (size_t)d0 * CQ + c0;
#pragma unroll
        for (int j = 0; j < 16; ++j) {
            acc[j] = fmaf(xv.x, w0[j],        acc[j]);
            acc[j] = fmaf(xv.y, w0[CQ + j],   acc[j]);
            acc[j] = fmaf(xv.z, w0[2*CQ + j], acc[j]);
            acc[j] = fmaf(xv.w, w0[3*CQ + j], acc[j]);
        }
    }
    float* outp = (isK ? k : q) + (size_t)row * CQ + c0;
#pragma unroll
    for (int j = 0; j < 16; ++j) outp[j] = acc[j] + bias[c0 + j];
}

// ---------------------------------------------------------------------------
// K1b: gates = sigmoid(x@Wg + bg)   one wave per row
// ---------------------------------------------------------------------------
__global__ __launch_bounds__(256) void gate_kernel(
    const float* __restrict__ x, const float* __restrict__ Wg,
    const float* __restrict__ bg, float* __restrict__ gout)
{
    int wave = threadIdx.x >> 6, lane = threadIdx.x & 63;
    int row  = blockIdx.x * 4 + wave;
    const float* xr = x + (size_t)row * DD;
    float s = 0.f;
#pragma unroll
    for (int i = 0; i < 4; ++i) {
        int d = (i * 64 + lane) * 4;
        float4 xv = *reinterpret_cast<const float4*>(xr + d);
        float4 wv = *reinterpret_cast<const float4*>(Wg + d);
        s = fmaf(xv.x, wv.x, s); s = fmaf(xv.y, wv.y, s);
        s = fmaf(xv.z, wv.z, s); s = fmaf(xv.w, wv.w, s);
    }
#pragma unroll
    for (int off = 32; off; off >>= 1) s += __shfl_xor(s, off);
    if (lane == 0) gout[row] = 1.f / (1.f + expf(-(s + bg[0])));
}

// ---------------------------------------------------------------------------
// K2: sim candidate generation.
// Block: 64 queries x 256 keys (2 subtiles of 128s). Thread tile 4q x 8s.
// A[128k][64q] (32KB, staged once, full K); B[64k][128s] (32KB, per K-half);
// sim tile (32KB) overlays B after gemm. Per k-step: 3 ds_read_b128 per
// 32 FMA-instr -> VALU-bound. Wave remapped 8x8 so A/B reads are <=2-way.
// Mask/gate applied at sim-write; scan reads rotated ((i+q)&31) -> <=4-way.
// Candidates only; exact f64 ranking in K3.
// ---------------------------------------------------------------------------
__global__ __launch_bounds__(256, 2) void simtopk_kernel(
    const float* __restrict__ qmat, const float* __restrict__ kmat,
    const float* __restrict__ gates, const float* __restrict__ am,
    float* __restrict__ pv, int* __restrict__ pi)
{
    __shared__ float Alds[CQ * 64];    // [c][q]  32 KB
    __shared__ float Blds[64 * 128];   // [c][s]  32 KB ; sim overlay

    const int tid = threadIdx.x;
    const int qt  = blockIdx.x;        // 0..127
    const int sp  = blockIdx.y;        // 0..15
    const int t0  = qt * 64;
    const int b   = t0 >> 12;

    // staging role
    const int lane31 = tid & 31;
    const int hi3    = tid >> 5;       // 0..7

    // gemm role: wave remap to 8x8
    const int wave = tid >> 6;
    const int lane = tid & 63;
    const int ty   = ((wave >> 1) << 3) | (lane >> 3);   // 0..15
    const int tx   = ((wave & 1) << 3) | (lane & 7);     // 0..15
    const int q0   = ty * 4;
    const int s0   = tx * 8;

    // per-row gate/mask for the 4 owned q rows (applied at sim-write)
    float g4r[4], mq4[4];
#pragma unroll
    for (int i = 0; i < 4; ++i) {
        g4r[i] = gates[t0 + q0 + i];
        mq4[i] = am[t0 + q0 + i];
    }
    const float scale = 0.08838834764831845f;  // 1/sqrt(128)

    // scan role: 4 threads per query
    const int scq = tid >> 2;          // 0..63
    const int sl  = tid & 3;
    float tv[TK]; int tix[TK];
#pragma unroll
    for (int j = 0; j < TK; ++j) { tv[j] = -3.0e38f; tix[j] = 0; }

    // ---- stage A once: [c][q], conflict-free writes (bank = q = lane31) ----
#pragma unroll
    for (int p = 0; p < 8; ++p) {
        int qr = lane31 + ((p & 1) << 5);            // 0..63
        int c4 = hi3 + ((p >> 1) << 3);              // 0..31
        float4 v4 = *reinterpret_cast<const float4*>(
            qmat + (size_t)(t0 + qr) * CQ + c4 * 4);
        Alds[(c4 * 4 + 0) * 64 + qr] = v4.x;
        Alds[(c4 * 4 + 1) * 64 + qr] = v4.y;
        Alds[(c4 * 4 + 2) * 64 + qr] = v4.z;
        Alds[(c4 * 4 + 3) * 64 + qr] = v4.w;
    }

    for (int st = 0; st < 2; ++st) {
        const int sbase = sp * 256 + st * 128;       // within-batch key base
        float4 acc[4][2];
#pragma unroll
        for (int i = 0; i < 4; ++i)
#pragma unroll
            for (int j = 0; j < 2; ++j)
                acc[i][j] = make_float4(0.f, 0.f, 0.f, 0.f);

        for (int h = 0; h < 2; ++h) {
            // ---- stage B half h: [c][s], conflict-free writes ----
#pragma unroll
            for (int p = 0; p < 8; ++p) {
                int sr  = lane31 + ((p & 3) << 5);    // 0..127
                int c4h = hi3 + ((p >> 2) << 3);      // 0..15
                float4 v4 = *reinterpret_cast<const float4*>(
                    kmat + (size_t)(b * TT + sbase + sr) * CQ + h * 64 + c4h * 4);
                Blds[(c4h * 4 + 0) * 128 + sr] = v4.x;
                Blds[(c4h * 4 + 1) * 128 + sr] = v4.y;
                Blds[(c4h * 4 + 2) * 128 + sr] = v4.z;
                Blds[(c4h * 4 + 3) * 128 + sr] = v4.w;
            }
            __syncthreads();

            // ---- gemm: 64 k-steps of this half ----
#pragma unroll 8
            for (int kk = 0; kk < 64; ++kk) {
                float4 a4 = *reinterpret_cast<const float4*>(
                    &Alds[(h * 64 + kk) * 64 + q0]);
                float4 b0 = *reinterpret_cast<const float4*>(
                    &Blds[kk * 128 + s0]);
                float4 b1 = *reinterpret_cast<const float4*>(
                    &Blds[kk * 128 + s0 + 4]);
#pragma unroll
                for (int i = 0; i < 4; ++i) {
                    float ai = (i == 0) ? a4.x : (i == 1) ? a4.y
                             : (i == 2) ? a4.z : a4.w;
                    acc[i][0].x = fmaf(ai, b0.x, acc[i][0].x);
                    acc[i][0].y = fmaf(ai, b0.y, acc[i][0].y);
                    acc[i][0].z = fmaf(ai, b0.z, acc[i][0].z);
                    acc[i][0].w = fmaf(ai, b0.w, acc[i][0].w);
                    acc[i][1].x = fmaf(ai, b1.x, acc[i][1].x);
                    acc[i][1].y = fmaf(ai, b1.y, acc[i][1].y);
                    acc[i][1].z = fmaf(ai, b1.z, acc[i][1].z);
                    acc[i][1].w = fmaf(ai, b1.w, acc[i][1].w);
                }
            }
            __syncthreads();   // done reading this B half
        }

        // ---- write masked+gated sim into Blds overlay: [64q][128s] ----
        {
            float ms8[8];
#pragma unroll
            for (int j = 0; j < 8; ++j) ms8[j] = am[b * TT + sbase + s0 + j];
#pragma unroll
            for (int i = 0; i < 4; ++i) {
                float sg = scale * g4r[i];
                float mn = -1e9f * g4r[i];
                float4 o0, o1;
                o0.x = (mq4[i] * ms8[0] == 0.f) ? mn : acc[i][0].x * sg;
                o0.y = (mq4[i] * ms8[1] == 0.f) ? mn : acc[i][0].y * sg;
                o0.z = (mq4[i] * ms8[2] == 0.f) ? mn : acc[i][0].z * sg;
                o0.w = (mq4[i] * ms8[3] == 0.f) ? mn : acc[i][0].w * sg;
                o1.x = (mq4[i] * ms8[4] == 0.f) ? mn : acc[i][1].x * sg;
                o1.y = (mq4[i] * ms8[5] == 0.f) ? mn : acc[i][1].y * sg;
                o1.z = (mq4[i] * ms8[6] == 0.f) ? mn : acc[i][1].z * sg;
                o1.w = (mq4[i] * ms8[7] == 0.f) ? mn : acc[i][1].w * sg;
                *reinterpret_cast<float4*>(&Blds[(q0 + i) * 128 + s0])     = o0;
                *reinterpret_cast<float4*>(&Blds[(q0 + i) * 128 + s0 + 4]) = o1;
            }
        }
        __syncthreads();

        // ---- scan: 4 thr/query, 32 keys each, rotated order (<=4-way) ----
        {
            const float* srow = &Blds[scq * 128];
#pragma unroll 4
            for (int i = 0; i < 32; ++i) {
                int so = (sl << 5) + ((i + scq) & 31);
                float val = srow[so];
                int sglob = sbase + so;
                if (val > tv[TK-1] || (val == tv[TK-1] && sglob < tix[TK-1]))
                    topk8_insert(tv, tix, val, sglob);
            }
        }
        __syncthreads();   // before next subtile overwrites sim
    }

    // ---- merge 4 slices per query; emit partial list for this split ----
    float* mv = Blds;                       // 256*9 = 2304 floats
    int*   mi = (int*)Alds;
#pragma unroll
    for (int j = 0; j < TK; ++j) { mv[tid * 9 + j] = tv[j]; mi[tid * 9 + j] = tix[j]; }
    __syncthreads();
    if (sl == 0) {
        for (int u = 1; u < 4; ++u) {
#pragma unroll
            for (int j = 0; j < TK; ++j) {
                float val = mv[(tid + u) * 9 + j];
                int   s   = mi[(tid + u) * 9 + j];
                if (val > tv[TK-1] || (val == tv[TK-1] && s < tix[TK-1]))
                    topk8_insert(tv, tix, val, s);
            }
        }
        int base = ((t0 + scq) * NCH + sp) * TK;
#pragma unroll
        for (int j = 0; j < TK; ++j) { pv[base + j] = tv[j]; pi[base + j] = tix[j]; }
    }
}

// ---------------------------------------------------------------------------
// K3: per query, rescore ALL 128 candidates in f64 (exact ranking), pick
// top-8 tie-aware, write idx (as float) + values, gather x rows.
// ---------------------------------------------------------------------------
__global__ __launch_bounds__(256) void merge_gather_kernel(
    const float* __restrict__ x,  const float* __restrict__ qm,
    const float* __restrict__ kmat, const float* __restrict__ gates,
    const float* __restrict__ am, const int* __restrict__ pi,
    float* __restrict__ out_g, float* __restrict__ out_i,
    float* __restrict__ out_v)
{
    int t = blockIdx.x;
    int b = t >> 12;

    __shared__ float  qrow[CQ];
    __shared__ double sval[NCH * TK];
    __shared__ int    scand[NCH * TK];
    __shared__ int    fidx[TK];

    if (threadIdx.x < 32) {
        *reinterpret_cast<float4*>(qrow + threadIdx.x * 4) =
            *reinterpret_cast<const float4*>(qm + (size_t)t * CQ + threadIdx.x * 4);
    }
    __syncthreads();

    if (threadIdx.x < NCH * TK) {
        int s = pi[(size_t)t * NCH * TK + threadIdx.x];
        const float* kr = kmat + (size_t)(b * TT + s) * CQ;
        double acc = 0.0;
#pragma unroll
        for (int d = 0; d < CQ; d += 4) {
            acc += (double)qrow[d + 0] * (double)kr[d + 0];
            acc += (double)qrow[d + 1] * (double)kr[d + 1];
            acc += (double)qrow[d + 2] * (double)kr[d + 2];
            acc += (double)qrow[d + 3] * (double)kr[d + 3];
        }
        double val;
        float ms  = am[b * TT + s];
        float mqq = am[t];
        if (mqq * ms == 0.f) val = -1e9;
        else                 val = acc * 0.08838834764831845;
        val *= (double)gates[t];
        sval[threadIdx.x]  = val;
        scand[threadIdx.x] = s;
    }
    __syncthreads();

    if (threadIdx.x == 0) {
        double v[TK]; int ix[TK];
#pragma unroll
        for (int j = 0; j < TK; ++j) { v[j] = -1.0e300; ix[j] = 0x7FFFFFFF; }
        for (int c = 0; c < NCH * TK; ++c) {
            double val = sval[c]; int s = scand[c];
            if (val > v[TK-1] || (val == v[TK-1] && s < ix[TK-1]))
                topk8d_insert(v, ix, val, s);
        }
#pragma unroll
        for (int j = 0; j < TK; ++j) {
            out_i[t * TK + j] = (float)ix[j];
            out_v[t * TK + j] = (float)v[j];
            fidx[j] = ix[j];
        }
    }
    __syncthreads();

#pragma unroll
    for (int j = 0; j < TK; ++j) {
        int row = fidx[j];
        float4 val4 = *reinterpret_cast<const float4*>(
            x + ((size_t)(b * TT + row)) * DD + threadIdx.x * 4);
        *reinterpret_cast<float4*>(
            out_g + ((size_t)(t * TK + j)) * DD + threadIdx.x * 4) = val4;
    }
}

// ---------------------------------------------------------------------------
extern "C" void kernel_launch(void* const* d_in, const int* in_sizes, int n_in,
                              void* d_out, int out_size, void* d_ws, size_t ws_size,
                              hipStream_t stream) {
    const float* x  = (const float*)d_in[0];
    const float* am = (const float*)d_in[1];
    const float* Wq = (const float*)d_in[2];
    const float* bq = (const float*)d_in[3];
    const float* Wk = (const float*)d_in[4];
    const float* bk = (const float*)d_in[5];
    const float* Wg = (const float*)d_in[6];
    const float* bg = (const float*)d_in[7];

    float* ws = (float*)d_ws;
    float* q  = ws;                              // NT*CQ      = 1048576
    float* k  = ws + 1048576;                    // NT*CQ      = 1048576
    float* g  = ws + 2097152;                    // NT         = 8192
    float* pv = ws + 2105344;                    // NT*NCH*TK  = 1048576
    int*   pi = (int*)(ws + 3153920);            // NT*NCH*TK  = 1048576

    float* out_g = (float*)d_out;                // [B,T,K,D] = 67108864
    float* out_i = out_g + 67108864;             // [B,T,K]   = 65536 (as float)
    float* out_v = out_i + 65536;                // [B,T,K]   = 65536

    proj_kernel<<<dim3(NT / 256, 16), 256, 0, stream>>>(x, Wq, bq, Wk, bk, q, k);
    gate_kernel<<<NT / 4, 256, 0, stream>>>(x, Wg, bg, g);
    simtopk_kernel<<<dim3(128, NCH), 256, 0, stream>>>(q, k, g, am, pv, pi);
    merge_gather_kernel<<<NT, 256, 0, stream>>>(x, q, k, g, am, pi,
                                                out_g, out_i, out_v);
}

// Round 8
// 356.078 us; speedup vs baseline: 1.5229x; 1.5229x over previous
//
#include <hip/hip_runtime.h>
#include <math.h>

// Problem constants (fixed by reference)
#define BB   2
#define TT   4096            // tokens per batch
#define NT   (BB*TT)         // 8192 total rows
#define DD   1024
#define CQ   128             // k_query dim
#define TK   8               // top_k
#define NCH  16              // s-splits (partial top-8 lists per query)

typedef __attribute__((ext_vector_type(8))) short short8b;  // 8 bf16 = 4 VGPR
typedef __attribute__((ext_vector_type(4))) float f32x4;

// strict insert: correct vs lax.top_k ties when candidates ascend in index
__device__ __forceinline__ void topk8_insert_strict(float (&v)[TK], int (&ix)[TK],
                                                    float val, int idx) {
    float cv = val; int ci = idx;
#pragma unroll
    for (int i = 0; i < TK; ++i) {
        bool sw = (cv > v[i]);
        float tv = v[i]; int ti = ix[i];
        v[i]  = sw ? cv : tv;  ix[i] = sw ? ci : ti;
        cv    = sw ? tv : cv;  ci    = sw ? ti : ci;
    }
}

// tie-break-aware insert (for merging lists whose index order is mixed)
__device__ __forceinline__ void topk8_insert(float (&v)[TK], int (&ix)[TK],
                                             float val, int idx) {
    float cv = val; int ci = idx;
#pragma unroll
    for (int i = 0; i < TK; ++i) {
        bool sw = (cv > v[i]) || (cv == v[i] && ci < ix[i]);
        float tv = v[i]; int ti = ix[i];
        v[i]  = sw ? cv : tv;  ix[i] = sw ? ci : ti;
        cv    = sw ? tv : cv;  ci    = sw ? ti : ci;
    }
}

// f64 tie-break-aware insert (final exact ranking)
__device__ __forceinline__ void topk8d_insert(double (&v)[TK], int (&ix)[TK],
                                              double val, int idx) {
    double cv = val; int ci = idx;
#pragma unroll
    for (int i = 0; i < TK; ++i) {
        bool sw = (cv > v[i]) || (cv == v[i] && ci < ix[i]);
        double tv = v[i]; int ti = ix[i];
        v[i]  = sw ? cv : tv;  ix[i] = sw ? ci : ti;
        cv    = sw ? tv : cv;  ci    = sw ? ti : ci;
    }
}

__device__ __forceinline__ unsigned int pack_bf16(float a, float b) {
    unsigned int ua = __float_as_uint(a), ub = __float_as_uint(b);
    return (ua >> 16) | (ub & 0xFFFF0000u);
}

// ---------------------------------------------------------------------------
// K1: q = x@Wq + bq ; k = x@Wk + bk  (unchanged — bit-exact passing math)
// ---------------------------------------------------------------------------
__global__ __launch_bounds__(256) void proj_kernel(
    const float* __restrict__ x,
    const float* __restrict__ Wq, const float* __restrict__ bq,
    const float* __restrict__ Wk, const float* __restrict__ bk,
    float* __restrict__ q, float* __restrict__ k)
{
    int row = blockIdx.x * 256 + threadIdx.x;        // 0..NT-1
    int cc  = blockIdx.y * 16;                       // combined col 0..255
    bool isK = cc >= CQ;
    const float* W    = isK ? Wk : Wq;
    const float* bias = isK ? bk : bq;
    int c0 = isK ? cc - CQ : cc;

    float acc[16];
#pragma unroll
    for (int j = 0; j < 16; ++j) acc[j] = 0.f;

    const float* xr = x + (size_t)row * DD;
    for (int d0 = 0; d0 < DD; d0 += 4) {
        float4 xv = *reinterpret_cast<const float4*>(xr + d0);
        const float* w0 = W + (size_t)d0 * CQ + c0;
#pragma unroll
        for (int j = 0; j < 16; ++j) {
            acc[j] = fmaf(xv.x, w0[j],        acc[j]);
            acc[j] = fmaf(xv.y, w0[CQ + j],   acc[j]);
            acc[j] = fmaf(xv.z, w0[2*CQ + j], acc[j]);
            acc[j] = fmaf(xv.w, w0[3*CQ + j], acc[j]);
        }
    }
    float* outp = (isK ? k : q) + (size_t)row * CQ + c0;
#pragma unroll
    for (int j = 0; j < 16; ++j) outp[j] = acc[j] + bias[c0 + j];
}

// ---------------------------------------------------------------------------
// K1b: gates = sigmoid(x@Wg + bg)   one wave per row (unchanged)
// ---------------------------------------------------------------------------
__global__ __launch_bounds__(256) void gate_kernel(
    const float* __restrict__ x, const float* __restrict__ Wg,
    const float* __restrict__ bg, float* __restrict__ gout)
{
    int wave = threadIdx.x >> 6, lane = threadIdx.x & 63;
    int row  = blockIdx.x * 4 + wave;
    const float* xr = x + (size_t)row * DD;
    float s = 0.f;
#pragma unroll
    for (int i = 0; i < 4; ++i) {
        int d = (i * 64 + lane) * 4;
        float4 xv = *reinterpret_cast<const float4*>(xr + d);
        float4 wv = *reinterpret_cast<const float4*>(Wg + d);
        s = fmaf(xv.x, wv.x, s); s = fmaf(xv.y, wv.y, s);
        s = fmaf(xv.z, wv.z, s); s = fmaf(xv.w, wv.w, s);
    }
#pragma unroll
    for (int off = 32; off; off >>= 1) s += __shfl_xor(s, off);
    if (lane == 0) gout[row] = 1.f / (1.f + expf(-(s + bg[0])));
}

// ---------------------------------------------------------------------------
// K2: MFMA bf16 candidate generation.
// Block: 64q x 256keys (4 chunks of 64). 4 waves; wave w = queries w*16..+15.
// LDS: Qb[64 q][128 k] bf16 (16KB) + Kb[64 s][128 k] bf16 (16KB), both with
// 16B-group XOR swizzle (g ^= row&7) -> conflict-free b128 reads AND writes.
// Per chunk per wave: 4 B-frag + 16 A-frag ds_read_b128, 16 MFMA
// (D: col=lane&15=query, row=key). Lane's 16 outputs/chunk = ONE query ->
// in-register strict top-8 (keys ascend). Candidates only; f64 ranking in K3.
// bf16 affects capture only: loss needs 8 better keys in one 256-key split
// plus a 0.4%-scale flip (P~1e-8).
// ---------------------------------------------------------------------------
__global__ __launch_bounds__(256, 4) void simtopk_kernel(
    const float* __restrict__ qmat, const float* __restrict__ kmat,
    const float* __restrict__ gates, const float* __restrict__ am,
    int* __restrict__ pi)
{
    __shared__ unsigned int Qb[64 * 64];   // 16KB: row = 64 u32 (128 bf16)
    __shared__ unsigned int Kb[64 * 64];   // 16KB

    const int tid  = threadIdx.x;
    const int lane = tid & 63;
    const int wv   = tid >> 6;             // wave 0..3
    const int qt   = blockIdx.x;           // 0..127
    const int sp   = blockIdx.y;           // 0..15
    const int t0   = qt * 64;
    const int b    = t0 >> 12;

    // staging role: row = tid>>2, groups (tid&3)+4j
    const int sr = tid >> 2;               // 0..63
    const int sg0 = tid & 3;

    // ---- stage Qb once ----
    {
        const float* src = qmat + (size_t)(t0 + sr) * CQ;
#pragma unroll
        for (int j = 0; j < 4; ++j) {
            int g = sg0 + j * 4;
            float4 f0 = *reinterpret_cast<const float4*>(src + g * 8);
            float4 f1 = *reinterpret_cast<const float4*>(src + g * 8 + 4);
            uint4 u;
            u.x = pack_bf16(f0.x, f0.y); u.y = pack_bf16(f0.z, f0.w);
            u.z = pack_bf16(f1.x, f1.y); u.w = pack_bf16(f1.z, f1.w);
            *reinterpret_cast<uint4*>(&Qb[sr * 64 + ((g ^ (sr & 7)) << 2)]) = u;
        }
    }
    // ---- stage Kb chunk 0 ----
    {
        const float* src = kmat + (size_t)(b * TT + sp * 256 + sr) * CQ;
#pragma unroll
        for (int j = 0; j < 4; ++j) {
            int g = sg0 + j * 4;
            float4 f0 = *reinterpret_cast<const float4*>(src + g * 8);
            float4 f1 = *reinterpret_cast<const float4*>(src + g * 8 + 4);
            uint4 u;
            u.x = pack_bf16(f0.x, f0.y); u.y = pack_bf16(f0.z, f0.w);
            u.z = pack_bf16(f1.x, f1.y); u.w = pack_bf16(f1.z, f1.w);
            *reinterpret_cast<uint4*>(&Kb[sr * 64 + ((g ^ (sr & 7)) << 2)]) = u;
        }
    }

    // gemm/scan role
    const int l15  = lane & 15;
    const int l4   = lane >> 4;            // quarter 0..3
    const int qrow = wv * 16 + l15;        // query within block, fixed/lane
    const int tq   = t0 + qrow;

    const float gate = gates[tq];
    const float mq   = am[tq];
    const float sgq  = 0.08838834764831845f * gate;
    const float mneg = -1e9f * gate;

    float tv[TK]; int tix[TK];
#pragma unroll
    for (int j = 0; j < TK; ++j) { tv[j] = -3.0e38f; tix[j] = 0; }

    const int koff = l4 * 4;               // key sub-offset within 16-row tile
    __syncthreads();

    for (int ck = 0; ck < 4; ++ck) {
        // ---- MFMA: D[key][query], 4 key-tiles, K=128 in 4 blocks ----
        f32x4 c0 = {0.f, 0.f, 0.f, 0.f};
        f32x4 c1 = {0.f, 0.f, 0.f, 0.f};
        f32x4 c2 = {0.f, 0.f, 0.f, 0.f};
        f32x4 c3 = {0.f, 0.f, 0.f, 0.f};
#pragma unroll
        for (int kb = 0; kb < 4; ++kb) {
            int gq = (kb * 4 + l4);
            short8b bq = *reinterpret_cast<const short8b*>(
                &Qb[qrow * 64 + (((gq) ^ (qrow & 7)) << 2)]);
            int r0 = l15,      p0 = ((gq) ^ (r0 & 7)) << 2;
            int r1 = 16 + l15, p1 = ((gq) ^ (r1 & 7)) << 2;
            int r2 = 32 + l15, p2 = ((gq) ^ (r2 & 7)) << 2;
            int r3 = 48 + l15, p3 = ((gq) ^ (r3 & 7)) << 2;
            short8b a0 = *reinterpret_cast<const short8b*>(&Kb[r0 * 64 + p0]);
            short8b a1 = *reinterpret_cast<const short8b*>(&Kb[r1 * 64 + p1]);
            short8b a2 = *reinterpret_cast<const short8b*>(&Kb[r2 * 64 + p2]);
            short8b a3 = *reinterpret_cast<const short8b*>(&Kb[r3 * 64 + p3]);
            c0 = __builtin_amdgcn_mfma_f32_16x16x32_bf16(a0, bq, c0, 0, 0, 0);
            c1 = __builtin_amdgcn_mfma_f32_16x16x32_bf16(a1, bq, c1, 0, 0, 0);
            c2 = __builtin_amdgcn_mfma_f32_16x16x32_bf16(a2, bq, c2, 0, 0, 0);
            c3 = __builtin_amdgcn_mfma_f32_16x16x32_bf16(a3, bq, c3, 0, 0, 0);
        }

        // ---- issue next chunk's staging loads (hide under scan) ----
        float4 pf[8];
        if (ck < 3) {
            const float* src = kmat +
                (size_t)(b * TT + sp * 256 + (ck + 1) * 64 + sr) * CQ;
#pragma unroll
            for (int j = 0; j < 4; ++j) {
                int g = sg0 + j * 4;
                pf[j * 2 + 0] = *reinterpret_cast<const float4*>(src + g * 8);
                pf[j * 2 + 1] = *reinterpret_cast<const float4*>(src + g * 8 + 4);
            }
        }

        // ---- in-register scan: 16 values, keys ascend (strict insert) ----
        {
            const int sB = sp * 256 + ck * 64;           // batch-local key base
            const float* amB = am + b * TT + sB;
            float val;
#define SCAN_TILE(CC, KT)                                                    \
            {                                                                \
                float4 amv = *reinterpret_cast<const float4*>(               \
                    amB + (KT) * 16 + koff);                                 \
                int kbase = sB + (KT) * 16 + koff;                           \
                val = (mq * amv.x == 0.f) ? mneg : CC.x * sgq;               \
                if (val > tv[TK-1]) topk8_insert_strict(tv, tix, val, kbase);\
                val = (mq * amv.y == 0.f) ? mneg : CC.y * sgq;               \
                if (val > tv[TK-1]) topk8_insert_strict(tv, tix, val, kbase+1);\
                val = (mq * amv.z == 0.f) ? mneg : CC.z * sgq;               \
                if (val > tv[TK-1]) topk8_insert_strict(tv, tix, val, kbase+2);\
                val = (mq * amv.w == 0.f) ? mneg : CC.w * sgq;               \
                if (val > tv[TK-1]) topk8_insert_strict(tv, tix, val, kbase+3);\
            }
            SCAN_TILE(c0, 0)
            SCAN_TILE(c1, 1)
            SCAN_TILE(c2, 2)
            SCAN_TILE(c3, 3)
#undef SCAN_TILE
        }
        __syncthreads();       // all MFMA reads of Kb complete

        if (ck < 3) {
#pragma unroll
            for (int j = 0; j < 4; ++j) {
                int g = sg0 + j * 4;
                uint4 u;
                u.x = pack_bf16(pf[j*2].x, pf[j*2].y);
                u.y = pack_bf16(pf[j*2].z, pf[j*2].w);
                u.z = pack_bf16(pf[j*2+1].x, pf[j*2+1].y);
                u.w = pack_bf16(pf[j*2+1].z, pf[j*2+1].w);
                *reinterpret_cast<uint4*>(&Kb[sr * 64 + ((g ^ (sr & 7)) << 2)]) = u;
            }
        }
        __syncthreads();       // staged writes visible
    }

    // ---- merge the 4 lane-quarters per query (tie-aware) ----
    float* mv = reinterpret_cast<float*>(Qb);   // 256 slots * 9
    int*   mi = reinterpret_cast<int*>(Kb);
    int slot = qrow * 4 + l4;
#pragma unroll
    for (int j = 0; j < TK; ++j) { mv[slot * 9 + j] = tv[j]; mi[slot * 9 + j] = tix[j]; }
    __syncthreads();
    if (l4 == 0) {
        for (int u = 1; u < 4; ++u) {
#pragma unroll
            for (int j = 0; j < TK; ++j) {
                float val = mv[(slot + u) * 9 + j];
                int   s   = mi[(slot + u) * 9 + j];
                if (val > tv[TK-1] || (val == tv[TK-1] && s < tix[TK-1]))
                    topk8_insert(tv, tix, val, s);
            }
        }
        int base = (tq * NCH + sp) * TK;
#pragma unroll
        for (int j = 0; j < TK; ++j) pi[base + j] = tix[j];
    }
}

// ---------------------------------------------------------------------------
// K3: per query, rescore ALL 128 candidates in f64 (exact ranking), pick
// top-8 tie-aware, write idx (as float) + values, gather x rows. (unchanged)
// ---------------------------------------------------------------------------
__global__ __launch_bounds__(256) void merge_gather_kernel(
    const float* __restrict__ x,  const float* __restrict__ qm,
    const float* __restrict__ kmat, const float* __restrict__ gates,
    const float* __restrict__ am, const int* __restrict__ pi,
    float* __restrict__ out_g, float* __restrict__ out_i,
    float* __restrict__ out_v)
{
    int t = blockIdx.x;
    int b = t >> 12;

    __shared__ float  qrow[CQ];
    __shared__ double sval[NCH * TK];
    __shared__ int    scand[NCH * TK];
    __shared__ int    fidx[TK];

    if (threadIdx.x < 32) {
        *reinterpret_cast<float4*>(qrow + threadIdx.x * 4) =
            *reinterpret_cast<const float4*>(qm + (size_t)t * CQ + threadIdx.x * 4);
    }
    __syncthreads();

    if (threadIdx.x < NCH * TK) {
        int s = pi[(size_t)t * NCH * TK + threadIdx.x];
        const float* kr = kmat + (size_t)(b * TT + s) * CQ;
        double acc = 0.0;
#pragma unroll
        for (int d = 0; d < CQ; d += 4) {
            acc += (double)qrow[d + 0] * (double)kr[d + 0];
            acc += (double)qrow[d + 1] * (double)kr[d + 1];
            acc += (double)qrow[d + 2] * (double)kr[d + 2];
            acc += (double)qrow[d + 3] * (double)kr[d + 3];
        }
        double val;
        float ms  = am[b * TT + s];
        float mqq = am[t];
        if (mqq * ms == 0.f) val = -1e9;
        else                 val = acc * 0.08838834764831845;
        val *= (double)gates[t];
        sval[threadIdx.x]  = val;
        scand[threadIdx.x] = s;
    }
    __syncthreads();

    if (threadIdx.x == 0) {
        double v[TK]; int ix[TK];
#pragma unroll
        for (int j = 0; j < TK; ++j) { v[j] = -1.0e300; ix[j] = 0x7FFFFFFF; }
        for (int c = 0; c < NCH * TK; ++c) {
            double val = sval[c]; int s = scand[c];
            if (val > v[TK-1] || (val == v[TK-1] && s < ix[TK-1]))
                topk8d_insert(v, ix, val, s);
        }
#pragma unroll
        for (int j = 0; j < TK; ++j) {
            out_i[t * TK + j] = (float)ix[j];
            out_v[t * TK + j] = (float)v[j];
            fidx[j] = ix[j];
        }
    }
    __syncthreads();

#pragma unroll
    for (int j = 0; j < TK; ++j) {
        int row = fidx[j];
        float4 val4 = *reinterpret_cast<const float4*>(
            x + ((size_t)(b * TT + row)) * DD + threadIdx.x * 4);
        *reinterpret_cast<float4*>(
            out_g + ((size_t)(t * TK + j)) * DD + threadIdx.x * 4) = val4;
    }
}

// ---------------------------------------------------------------------------
extern "C" void kernel_launch(void* const* d_in, const int* in_sizes, int n_in,
                              void* d_out, int out_size, void* d_ws, size_t ws_size,
                              hipStream_t stream) {
    const float* x  = (const float*)d_in[0];
    const float* am = (const float*)d_in[1];
    const float* Wq = (const float*)d_in[2];
    const float* bq = (const float*)d_in[3];
    const float* Wk = (const float*)d_in[4];
    const float* bk = (const float*)d_in[5];
    const float* Wg = (const float*)d_in[6];
    const float* bg = (const float*)d_in[7];

    float* ws = (float*)d_ws;
    float* q  = ws;                              // NT*CQ      = 1048576
    float* k  = ws + 1048576;                    // NT*CQ      = 1048576
    float* g  = ws + 2097152;                    // NT         = 8192
    int*   pi = (int*)(ws + 2105344);            // NT*NCH*TK  = 1048576

    float* out_g = (float*)d_out;                // [B,T,K,D] = 67108864
    float* out_i = out_g + 67108864;             // [B,T,K]   = 65536 (as float)
    float* out_v = out_i + 65536;                // [B,T,K]   = 65536

    proj_kernel<<<dim3(NT / 256, 16), 256, 0, stream>>>(x, Wq, bq, Wk, bk, q, k);
    gate_kernel<<<NT / 4, 256, 0, stream>>>(x, Wg, bg, g);
    simtopk_kernel<<<dim3(128, NCH), 256, 0, stream>>>(q, k, g, am, pi);
    merge_gather_kernel<<<NT, 256, 0, stream>>>(x, q, k, g, am, pi,
                                                out_g, out_i, out_v);
}